// Round 8
// baseline (418.695 us; speedup 1.0000x reference)
//
#include <hip/hip_runtime.h>
#include <hip/hip_bf16.h>

typedef __hip_bfloat16 bf16;
typedef __attribute__((ext_vector_type(8))) short bf16x8;   // 8 bf16 = 4 VGPR
typedef __attribute__((ext_vector_type(4))) float f32x4;

#define N_NODES   131072
#define N_GRAPHS  4096
#define FIN       256
#define FH        512
#define NPAD      176     // 164 padded to 11*16
#define NREAL     164

// ---------- workspace layout (bytes) ----------
#define OFF_XB     0UL            // bf16 131072x256 = 67,108,864
#define OFF_XENDB  67108864UL     // bf16 4096x256   =  2,097,152
#define OFF_W1A    69206016UL     // bf16 512x256    =    262,144
#define OFF_BCAT   69468160UL     // bf16 1024x256   =    524,288
#define OFF_WXB    69992448UL     // bf16 176x512    =    180,224
#define OFF_STATS  70172672UL     // f32  4x512      =      8,192
#define OFF_XXE    70180864UL     // f32  4096
#define OFF_CCAT   70197248UL     // f32  4096x1024  = 16,777,216
#define OFF_H      86974464UL     // bf16 131072x512 = 134,217,728
// total ~211 MB

__device__ __forceinline__ void gld_lds16(const void* g, void* l) {
  __builtin_amdgcn_global_load_lds(
      (const __attribute__((address_space(1))) void*)g,
      (__attribute__((address_space(3))) void*)l, 16, 0, 0);
}

__device__ __forceinline__ float bf2f(unsigned short u) {
  unsigned int x = ((unsigned int)u) << 16; float f;
  __builtin_memcpy(&f, &x, 4); return f;
}
__device__ __forceinline__ unsigned short f2bf(float f) {
  bf16 h = __float2bfloat16(f); unsigned short u;
  __builtin_memcpy(&u, &h, 2); return u;
}

// ---------- K0: weight casts + zero stats ----------
__global__ __launch_bounds__(256) void k_wcast(
    const float* __restrict__ W_h, const float* __restrict__ W_ht,
    const float* __restrict__ W_x,
    bf16* __restrict__ W1a, bf16* __restrict__ Bcat, bf16* __restrict__ Wxb,
    float* __restrict__ stats)
{
  int i = blockIdx.x * 256 + threadIdx.x;            // grid 1024 -> 262144
  if (i < 2048) stats[i] = 0.f;                      // s1m,s2m,s1e,s2e
  if (i < 512 * 512) {
    int of = i >> 9, ic = i & 511;
    float v = W_h[i];
    if (ic < 256) W1a[of * 256 + ic] = __float2bfloat16(v);
    else          Bcat[of * 256 + (ic - 256)] = __float2bfloat16(v);
  }
  if (i < 512 * 256) Bcat[512 * 256 + i] = __float2bfloat16(W_ht[i]);
  if (i < NPAD * 512) {
    int n = i >> 9;
    Wxb[i] = (n < NREAL) ? __float2bfloat16(W_x[i]) : __float2bfloat16(0.f);
  }
}

// ---------- K1: per-graph mean of X + bf16 cast of X (fused) ----------
__global__ __launch_bounds__(256) void k_xend(
    const float* __restrict__ X, const int* __restrict__ NX,
    bf16* __restrict__ Xb, bf16* __restrict__ X_endb)
{
  int g = blockIdx.x;                 // 4096
  int t = threadIdx.x;
  int cg = t & 63;                    // cols cg*4..+3
  int rg = t >> 6;                    // rows rg*8..+7
  const float* Xg = X + (long)g * 32 * FIN;
  bf16* Xbg = Xb + (long)g * 32 * FIN;
  float4 s = {0.f, 0.f, 0.f, 0.f};
  #pragma unroll
  for (int r = 0; r < 8; ++r) {
    int off = (rg * 8 + r) * FIN + cg * 4;
    float4 v = *(const float4*)(Xg + off);
    s.x += v.x; s.y += v.y; s.z += v.z; s.w += v.w;
    ushort4 u = {f2bf(v.x), f2bf(v.y), f2bf(v.z), f2bf(v.w)};
    *(ushort4*)(Xbg + off) = u;
  }
  __shared__ float4 red[256];
  red[t] = s;
  __syncthreads();
  if (t < 64) {
    float4 a = red[t], b = red[t + 64], c = red[t + 128], d = red[t + 192];
    float inv = 1.f / (float)NX[g];
    float4 m = {(a.x + b.x + c.x + d.x) * inv, (a.y + b.y + c.y + d.y) * inv,
                (a.z + b.z + c.z + d.z) * inv, (a.w + b.w + c.w + d.w) * inv};
    ushort4 u = {f2bf(m.x), f2bf(m.y), f2bf(m.z), f2bf(m.w)};
    *(ushort4*)(X_endb + (long)g * FIN + t * 4) = u;
  }
}

// ---------- GEMM0: Ccat = X_endb @ [W1b; W_ht]^T  (M=4096,N=1024,K=256) ------
// + fused column stats for cols 512..1023 (the Hend half)
__global__ __launch_bounds__(256, 2) void gemm0(
    const bf16* __restrict__ A, const bf16* __restrict__ B,
    float* __restrict__ Cout, float* __restrict__ s1e, float* __restrict__ s2e)
{
  const int bid = blockIdx.x;                 // 256
  const int blkM = bid >> 3, blkN = bid & 7;
  const int tid = threadIdx.x;
  const int w = tid >> 6, lane = tid & 63;
  const int wm = w >> 1, wn = w & 1;

  __shared__ __align__(16) bf16 lA[128 * 32];
  __shared__ __align__(16) bf16 lB[128 * 32];
  __shared__ float sred[2][2][128];

  f32x4 acc[4][4] = {};
  const int rS = lane >> 2;
  const int cS = (lane & 3) * 8;
  const long baseA = (long)blkM * 128;
  const long baseB = (long)blkN * 128;

  for (int kk = 0; kk < FIN; kk += 32) {
    #pragma unroll
    for (int c = 0; c < 2; ++c) {
      int chunk = 2 * w + c;
      gld_lds16(A + (baseA + chunk * 16 + rS) * FIN + kk + cS, &lA[chunk * 16 * 32]);
      gld_lds16(B + (baseB + chunk * 16 + rS) * FIN + kk + cS, &lB[chunk * 16 * 32]);
    }
    __syncthreads();
    bf16x8 a8[4], b8[4];
    #pragma unroll
    for (int t = 0; t < 4; ++t) {
      a8[t] = *(const bf16x8*)&lA[(wm * 64 + t * 16 + (lane & 15)) * 32 + (lane >> 4) * 8];
      b8[t] = *(const bf16x8*)&lB[(wn * 64 + t * 16 + (lane & 15)) * 32 + (lane >> 4) * 8];
    }
    #pragma unroll
    for (int tm = 0; tm < 4; ++tm)
      #pragma unroll
      for (int tn = 0; tn < 4; ++tn)
        acc[tm][tn] = __builtin_amdgcn_mfma_f32_16x16x32_bf16(a8[tm], b8[tn], acc[tm][tn], 0, 0, 0);
    __syncthreads();
  }

  const int rowq = (lane >> 4) * 4;
  const int coll = lane & 15;
  float p1[4] = {0.f, 0.f, 0.f, 0.f}, p2[4] = {0.f, 0.f, 0.f, 0.f};
  #pragma unroll
  for (int tm = 0; tm < 4; ++tm)
    #pragma unroll
    for (int tn = 0; tn < 4; ++tn)
      #pragma unroll
      for (int r = 0; r < 4; ++r) {
        long row = baseA + wm * 64 + tm * 16 + rowq + r;
        int col = (int)baseB + wn * 64 + tn * 16 + coll;
        float v = acc[tm][tn][r];
        Cout[row * 1024 + col] = v;
        p1[tn] += v; p2[tn] += v * v;
      }

  if (blkN >= 4) {
    #pragma unroll
    for (int tn = 0; tn < 4; ++tn) {
      float q1 = p1[tn], q2 = p2[tn];
      q1 += __shfl_xor(q1, 16); q1 += __shfl_xor(q1, 32);
      q2 += __shfl_xor(q2, 16); q2 += __shfl_xor(q2, 32);
      if (lane < 16) {
        sred[wm][0][wn * 64 + tn * 16 + lane] = q1;
        sred[wm][1][wn * 64 + tn * 16 + lane] = q2;
      }
    }
    __syncthreads();
    int st = tid >> 7, c = tid & 127;
    float v = sred[0][st][c] + sred[1][st][c];
    atomicAdd((st ? s2e : s1e) + (blkN - 4) * 128 + c, v);
  }
}

// ---------- K3: end path, folded finalize ----------
__global__ __launch_bounds__(256) void k_xxend(
    const float* __restrict__ Ccat, const float* __restrict__ s1e,
    const float* __restrict__ s2e, const float* __restrict__ g_ht,
    const float* __restrict__ b_ht, const float* __restrict__ Wxt,
    const float* __restrict__ bxt, float* __restrict__ Xxe)
{
  __shared__ float aL[512], cL[512];
  int tid = threadIdx.x;
  #pragma unroll
  for (int i = tid; i < 512; i += 256) {
    float mean = s1e[i] * 2.44140625e-4f;
    float var = s2e[i] * 2.44140625e-4f - mean * mean;
    float a = g_ht[i] / sqrtf(var + 1e-5f);
    aL[i] = a; cL[i] = b_ht[i] - mean * a;
  }
  __syncthreads();
  int w = tid >> 6, lane = tid & 63;
  int g = blockIdx.x * 4 + w;          // grid 1024
  const float* h = Ccat + (long)g * 1024 + 512;
  float acc = 0.f;
  #pragma unroll
  for (int i = 0; i < 8; ++i) {
    int j = lane + i * 64;
    float x = fmaxf(aL[j] * h[j] + cL[j], 0.f);
    acc += x * Wxt[j];
  }
  #pragma unroll
  for (int off = 32; off; off >>= 1) acc += __shfl_xor(acc, off);
  if (lane == 0) Xxe[g] = expf(acc + bxt[0]);
}

// ---------- GEMM1 v7: v6 + conflict-free ring via pre-swizzled source -------
// Identical structure/ledger to v6 (passed R6). Only change: each 1KB ring
// unit is now laid out [4 k-slots][16 rows][16B] instead of [16 rows][64B].
// gld_lds writes lane-linearly, so the GLOBAL per-lane address is permuted
// (lane = hi*16+row instead of row*4+kslot); the address SET per unit is
// identical (16 rows x 64B), so coalescing is unchanged. Fragment ds_read
// becomes lane-consecutive 16B -> 0 bank conflicts (was 8-way).
#define G1WAIT(WN) asm volatile("s_waitcnt vmcnt(" #WN ")" ::: "memory");

#define G1S(MTV, KS, WN)                                                       \
  {                                                                            \
    G1WAIT(WN)                                                                 \
    if ((KS) == 0) {                                                           \
      long g0_ = ((long)(MTV)) * 2 + (rowbase >> 5);                           \
      _Pragma("unroll")                                                        \
      for (int a_ = 0; a_ < 2; ++a_)                                           \
        _Pragma("unroll")                                                      \
        for (int j_ = 0; j_ < 4; ++j_)                                         \
          ct[a_][j_] = Ccat[(g0_ + a_) * 1024 + w * 64 + j_ * 16 + coll];      \
    }                                                                          \
    { int tgt_ = (MTV) * 8 + (KS) + 2; if (tgt_ > 63) tgt_ = 63;               \
      const bf16* src_ = Xb + (rowbase + (long)(tgt_ >> 3) * 64 + coll) * FIN  \
                         + (tgt_ & 7) * 32 + hi * 8;                           \
      _Pragma("unroll")                                                        \
      for (int c_ = 0; c_ < 4; ++c_)                                           \
        gld_lds16(src_ + c_ * 16 * FIN, &ring[w][((KS) + 2) & 3][c_ * 512]); } \
    bf16x8 a8_[4];                                                             \
    _Pragma("unroll")                                                          \
    for (int t_ = 0; t_ < 4; ++t_)                                             \
      a8_[t_] = *(const bf16x8*)&ring[w][(KS) & 3][t_ * 512                    \
                                                   + (hi * 16 + coll) * 8];    \
    _Pragma("unroll")                                                          \
    for (int t_ = 0; t_ < 4; ++t_)                                             \
      _Pragma("unroll")                                                        \
      for (int j_ = 0; j_ < 4; ++j_)                                           \
        acc[t_][j_] = __builtin_amdgcn_mfma_f32_16x16x32_bf16(                 \
            a8_[t_], b8[j_][KS], acc[t_][j_], 0, 0, 0);                        \
  }

__global__ __launch_bounds__(512, 2) void gemm1(
    const bf16* __restrict__ Xb, const bf16* __restrict__ W1a,
    const float* __restrict__ Ccat, bf16* __restrict__ H,
    float* __restrict__ s1m, float* __restrict__ s2m)
{
  const int bid = blockIdx.x;            // 256
  const int tid = threadIdx.x;
  const int w = tid >> 6, lane = tid & 63;
  const int hi = lane >> 4;
  const int coll = lane & 15;

  __shared__ __align__(16) bf16 ring[8][4][2048];   // per-wave private ring

  // ---- B panel -> registers (64 cols x 256 K = 128 VGPR) ----
  bf16x8 b8[4][8];
  #pragma unroll
  for (int j = 0; j < 4; ++j)
    #pragma unroll
    for (int ks = 0; ks < 8; ++ks)
      b8[j][ks] = *(const bf16x8*)(W1a + (w * 64 + j * 16 + coll) * FIN
                                   + ks * 32 + hi * 8);

  // ---- prologue: stage steps 0,1 into slots 0,1 (swizzled source) ----
  const long rowbase = (long)bid * 512;
  #pragma unroll
  for (int s = 0; s < 2; ++s)
    #pragma unroll
    for (int c = 0; c < 4; ++c)
      gld_lds16(Xb + (rowbase + c * 16 + coll) * FIN + s * 32 + hi * 8,
                &ring[w][s][c * 512]);

  f32x4 acc[4][4] = {};
  float p1[4] = {0.f, 0.f, 0.f, 0.f}, p2[4] = {0.f, 0.f, 0.f, 0.f};
  float ct[2][4];

  #pragma unroll 1
  for (int mt = 0; mt < 8; ++mt) {
    G1S(mt, 0, 4)  G1S(mt, 1, 12) G1S(mt, 2, 4) G1S(mt, 3, 4)
    G1S(mt, 4, 4)  G1S(mt, 5, 4)  G1S(mt, 6, 4) G1S(mt, 7, 4)

    // ---- epilogue: registers only (no sync, no drain) ----
    const long rtile = rowbase + (long)mt * 64;
    #pragma unroll
    for (int t = 0; t < 4; ++t)
      #pragma unroll
      for (int j = 0; j < 4; ++j) {
        int col = w * 64 + j * 16 + coll;
        #pragma unroll
        for (int r = 0; r < 4; ++r) {
          float h = acc[t][j][r] + ct[t >> 1][j];
          H[(rtile + t * 16 + hi * 4 + r) * FH + col] = __float2bfloat16(h);
          p1[j] += h; p2[j] += h * h;
        }
        acc[t][j][0] = 0.f; acc[t][j][1] = 0.f;
        acc[t][j][2] = 0.f; acc[t][j][3] = 0.f;
      }
  }

  // ---- column stats: one atomic set per wave ----
  #pragma unroll
  for (int j = 0; j < 4; ++j) {
    float q1 = p1[j], q2 = p2[j];
    q1 += __shfl_xor(q1, 16); q1 += __shfl_xor(q1, 32);
    q2 += __shfl_xor(q2, 16); q2 += __shfl_xor(q2, 32);
    if (lane < 16) {
      atomicAdd(s1m + w * 64 + j * 16 + lane, q1);
      atomicAdd(s2m + w * 64 + j * 16 + lane, q2);
    }
  }
}

// ---------- GEMM2 v3: Wxb in LDS halves (2 restages total), per-wave lA, ----
// conflict-free fragment layout, depth-2 H reg-prefetch, no in-loop barriers.
// Grid 512 x 512 threads (8 waves, 1 blk/CU). Block = 256 rows (8 graphs,
// 1 graph per wave). lB = 90 KB = one K-half of all 176 cols, unit layout
// [ks][o] of [4 kslot][16 col][16B] (staged with pre-swizzled source ->
// ds_read_b128 conflict-free). lA = per-wave 2 KB, same unit layout.
__global__ __launch_bounds__(512, 2) void gemm2(
    const bf16* __restrict__ Hraw, const bf16* __restrict__ Wxb,
    const float* __restrict__ s1m, const float* __restrict__ s2m,
    const float* __restrict__ g_h, const float* __restrict__ b_h,
    const float* __restrict__ b_x, const float* __restrict__ Xxe,
    float* __restrict__ outA, float* __restrict__ outC, float* __restrict__ outE)
{
  const int blk = blockIdx.x;          // 512
  const int tid = threadIdx.x;
  const int w = tid >> 6, lane = tid & 63;
  const int rS = lane >> 2;            // H-load row-in-16
  const int cS = (lane & 3) * 8;       // H-load k elem offset
  const int hi = lane >> 4;
  const int coll = lane & 15;

  __shared__ __align__(16) bf16 lB[88 * 512];    // 90112 B
  __shared__ __align__(16) bf16 lA[8][1024];     // 16 KB, per-wave private
  __shared__ float aL[512], cL[512];

  {
    float mean = s1m[tid] * 7.62939453125e-6f;
    float var = s2m[tid] * 7.62939453125e-6f - mean * mean;
    float a = g_h[tid] / sqrtf(var + 1e-5f);
    aL[tid] = a; cL[tid] = b_h[tid] - mean * a;
  }

  // ---- stage B half 0 (88 units, swizzled source) ----
  #pragma unroll
  for (int j = 0; j < 11; ++j) {
    int u = j * 8 + w;                 // 0..87
    int ks = u / 11, o = u - ks * 11;
    gld_lds16(Wxb + (o * 16 + coll) * FH + ks * 32 + hi * 8, &lB[u * 512]);
  }

  // ---- H prologue: transform step 0 -> lA; prefetch steps 1,2 to regs ----
  const long wrow = (long)blk * 256 + w * 32;

  #define G2X(rawv, kof)                                                     \
    { f32x4 a0_ = *(const f32x4*)&aL[(kof) + cS];                            \
      f32x4 a1_ = *(const f32x4*)&aL[(kof) + cS + 4];                        \
      f32x4 c0_ = *(const f32x4*)&cL[(kof) + cS];                            \
      f32x4 c1_ = *(const f32x4*)&cL[(kof) + cS + 4];                        \
      unsigned short* u_ = (unsigned short*)&(rawv);                         \
      _Pragma("unroll")                                                      \
      for (int q_ = 0; q_ < 4; ++q_) {                                       \
        float v_ = bf2f(u_[q_]);                                             \
        u_[q_] = f2bf(fmaxf(a0_[q_] * v_ + c0_[q_], 0.f));                   \
      }                                                                      \
      _Pragma("unroll")                                                      \
      for (int q_ = 0; q_ < 4; ++q_) {                                       \
        float v_ = bf2f(u_[4 + q_]);                                         \
        u_[4 + q_] = f2bf(fmaxf(a1_[q_] * v_ + c1_[q_], 0.f));               \
      }                                                                      \
    }

  uint4 hA[2], hB[2];
  __syncthreads();                      // aL/cL visible to all
  #pragma unroll
  for (int c = 0; c < 2; ++c) {
    uint4 raw = *(const uint4*)(Hraw + (wrow + c * 16 + rS) * FH + cS);
    G2X(raw, 0)
    *(uint4*)&lA[w][c * 512 + ((lane & 3) * 16 + rS) * 8] = raw;
  }
  #pragma unroll
  for (int c = 0; c < 2; ++c)
    hA[c] = *(const uint4*)(Hraw + (wrow + c * 16 + rS) * FH + 32 + cS);
  #pragma unroll
  for (int c = 0; c < 2; ++c)
    hB[c] = *(const uint4*)(Hraw + (wrow + c * 16 + rS) * FH + 64 + cS);

  asm volatile("s_waitcnt vmcnt(0)" ::: "memory");
  __syncthreads();                      // lB half 0 ready

  f32x4 acc[2][11] = {};

  #pragma unroll 1
  for (int half = 0; half < 2; ++half) {
    #pragma unroll
    for (int ks = 0; ks < 8; ++ks) {
      const int step = half * 8 + ks;
      // 1. read current A fragments (prepared last step)
      bf16x8 a8[2];
      #pragma unroll
      for (int t = 0; t < 2; ++t)
        a8[t] = *(const bf16x8*)&lA[w][t * 512 + (hi * 16 + coll) * 8];
      // 2. transform next step into lA; rotate prefetch regs
      if (step < 15) {
        #pragma unroll
        for (int c = 0; c < 2; ++c) {
          uint4 raw = hA[c];
          G2X(raw, (step + 1) * 32)
          *(uint4*)&lA[w][c * 512 + ((lane & 3) * 16 + rS) * 8] = raw;
        }
        hA[0] = hB[0]; hA[1] = hB[1];
        if (step < 13) {
          #pragma unroll
          for (int c = 0; c < 2; ++c)
            hB[c] = *(const uint4*)(Hraw + (wrow + c * 16 + rS) * FH
                                    + (step + 3) * 32 + cS);
        }
      }
      // 3. B fragments + MFMA
      #pragma unroll
      for (int tn = 0; tn < 11; ++tn) {
        bf16x8 bb = *(const bf16x8*)&lB[(ks * 11 + tn) * 512
                                        + (hi * 16 + coll) * 8];
        #pragma unroll
        for (int tm = 0; tm < 2; ++tm)
          acc[tm][tn] = __builtin_amdgcn_mfma_f32_16x16x32_bf16(
              a8[tm], bb, acc[tm][tn], 0, 0, 0);
      }
    }
    if (half == 0) {
      __syncthreads();                  // all reads of lB half 0 done
      #pragma unroll
      for (int j = 0; j < 11; ++j) {
        int u = j * 8 + w;
        int ks = u / 11, o = u - ks * 11;
        gld_lds16(Wxb + (o * 16 + coll) * FH + 256 + ks * 32 + hi * 8,
                  &lB[u * 512]);
      }
      asm volatile("s_waitcnt vmcnt(0)" ::: "memory");
      __syncthreads();                  // lB half 1 ready
    }
  }

  // ---- epilogue: exp + per-graph softmax (graph == wave) ----
  const int rowq = hi * 4;
  const int g = blk * 8 + w;
  float psum = 0.f;
  #pragma unroll
  for (int tn = 0; tn < 11; ++tn) {
    int col = tn * 16 + coll;
    bool valid = col < NREAL;
    float bx = valid ? b_x[col] : 0.f;
    #pragma unroll
    for (int tm = 0; tm < 2; ++tm)
      #pragma unroll
      for (int r = 0; r < 4; ++r) {
        float p = valid ? expf(acc[tm][tn][r] + bx) : 0.f;
        acc[tm][tn][r] = p;
        psum += p;
      }
  }
  #pragma unroll
  for (int off = 32; off; off >>= 1) psum += __shfl_xor(psum, off);
  float Xe = Xxe[g];
  float inv = 1.0f / (psum + Xe);
  if (lane == 0) outE[g] = Xe * inv;

  #pragma unroll
  for (int tn = 0; tn < 11; ++tn) {
    int col = tn * 16 + coll;
    if (col >= NREAL) continue;
    #pragma unroll
    for (int tm = 0; tm < 2; ++tm)
      #pragma unroll
      for (int r = 0; r < 4; ++r) {
        long row = wrow + tm * 16 + rowq + r;
        float v = acc[tm][tn][r] * inv;
        if (col >= 4) outA[row * 160 + (col - 4)] = v;
        else          outC[row * 4 + col] = v;
      }
  }
}

extern "C" void kernel_launch(void* const* d_in, const int* in_sizes, int n_in,
                              void* d_out, int out_size, void* d_ws, size_t ws_size,
                              hipStream_t stream)
{
  const float* X    = (const float*)d_in[0];
  const int*   NX   = (const int*)d_in[1];      // int64 in ref -> int32 in harness
  const float* W_h  = (const float*)d_in[3];
  const float* g_h  = (const float*)d_in[4];
  const float* b_h  = (const float*)d_in[5];
  const float* W_ht = (const float*)d_in[6];
  const float* g_ht = (const float*)d_in[7];
  const float* b_ht = (const float*)d_in[8];
  const float* W_x  = (const float*)d_in[9];
  const float* b_x  = (const float*)d_in[10];
  const float* W_xt = (const float*)d_in[11];
  const float* b_xt = (const float*)d_in[12];

  char* ws = (char*)d_ws;
  bf16*  Xb    = (bf16*)(ws + OFF_XB);
  bf16*  X_endb= (bf16*)(ws + OFF_XENDB);
  bf16*  W1a   = (bf16*)(ws + OFF_W1A);
  bf16*  Bcat  = (bf16*)(ws + OFF_BCAT);
  bf16*  Wxb   = (bf16*)(ws + OFF_WXB);
  float* stats = (float*)(ws + OFF_STATS);
  float* s1m = stats, *s2m = stats + 512, *s1e = stats + 1024, *s2e = stats + 1536;
  float* Xxe   = (float*)(ws + OFF_XXE);
  float* Ccat  = (float*)(ws + OFF_CCAT);
  bf16*  H     = (bf16*)(ws + OFF_H);

  float* outA = (float*)d_out;                 // append: 131072*160
  float* outC = outA + (long)N_NODES * 160;    // connect: 131072*4
  float* outE = outC + (long)N_NODES * 4;      // end: 4096

  k_wcast<<<1024, 256, 0, stream>>>(W_h, W_ht, W_x, W1a, Bcat, Wxb, stats);
  k_xend<<<N_GRAPHS, 256, 0, stream>>>(X, NX, Xb, X_endb);
  gemm0<<<256, 256, 0, stream>>>(X_endb, Bcat, Ccat, s1e, s2e);
  k_xxend<<<1024, 256, 0, stream>>>(Ccat, s1e, s2e, g_ht, b_ht, W_xt, b_xt, Xxe);
  gemm1<<<256, 512, 0, stream>>>(Xb, W1a, Ccat, H, s1m, s2m);
  gemm2<<<512, 512, 0, stream>>>(H, Wxb, s1m, s2m, g_h, b_h, b_x, Xxe, outA, outC, outE);
}